// Round 2
// baseline (329.657 us; speedup 1.0000x reference)
//
#include <hip/hip_runtime.h>
#include <stdint.h>

typedef __attribute__((ext_vector_type(4))) float f32x4;
typedef __attribute__((ext_vector_type(8))) short bf16x8;
typedef __attribute__((ext_vector_type(2))) unsigned int u32x2;

#define B_SZ   32
#define L_AUD  441000
#define PAD_A  1024
#define LP     443048          // L_AUD + 2*PAD_A
#define T_FR   862
#define J_TOT  27584           // B_SZ * T_FR
#define F_BINS 1025
#define NFFT   2048
#define NB     64
#define FPAD   1152            // 9 * 128
#define NT_J   108             // 27648 / 256
#define NT_F   9
#define ROWB   886096          // LP * 2 bytes per xbp row

#define XBP_OFF   0
#define XBP_BYTES (B_SZ * LP * 2)             // 28,355,072
#define WBT_OFF   XBP_BYTES
#define WBT_BYTES (NT_F * 32 * 2 * 16384)     // 9,437,184
#define GB_OFF    (WBT_OFF + WBT_BYTES)
#define GB_BYTES  (NB * FPAD * 2)             // 147,456
#define WS_NEED   (GB_OFF + GB_BYTES)

__device__ __forceinline__ uint16_t f2bf(float f) {
  union { float f; uint32_t u; } c; c.f = f;
  uint32_t r = c.u + 0x7FFFu + ((c.u >> 16) & 1u);
  return (uint16_t)(r >> 16);
}

__device__ __forceinline__ f32x4 mfma16(bf16x8 a, bf16x8 b, f32x4 c) {
  return __builtin_amdgcn_mfma_f32_16x16x32_bf16(a, b, c, 0, 0, 0);
}

#define GLD16(g, l) __builtin_amdgcn_global_load_lds( \
    (__attribute__((address_space(1))) void*)(g),     \
    (__attribute__((address_space(3))) void*)(l), 16, 0, 0)

// ---- prep: reflect-padded bf16 audio ------------------------------------
__global__ __launch_bounds__(256) void build_xbp(const float* __restrict__ x,
                                                 uint16_t* __restrict__ xbp) {
  int i = blockIdx.x * 256 + threadIdx.x;     // [32][443048] element
  int b = i / LP;
  int p = i - b * LP;
  int s = p - PAD_A;
  s = s < 0 ? -s : s;
  s = s >= L_AUD ? (2 * L_AUD - 2 - s) : s;
  xbp[i] = f2bf(x[b * L_AUD + s]);
}

// ---- prep: W blobs. blob = (fb*32 + kkt)*2 + half, 16 KB each, laid out
// exactly in linear staging order: byte = lr*128 + ((kl*2) ^ ((lr&7)<<4)).
// Row mapping inside half: plane = lr>>6 (0 sin, 1 cos), f = fb*128 + half*64 + (lr&63)
__global__ __launch_bounds__(256) void build_wbt(const float* __restrict__ wsin,
                                                 const float* __restrict__ wcos,
                                                 char* __restrict__ wbt) {
  int idx = blockIdx.x * 256 + threadIdx.x;   // bf16 element index
  int e = idx & 8191;
  int blob = idx >> 13;
  int half = blob & 1;
  int kkt = (blob >> 1) & 31;
  int fb = blob >> 6;
  int lr = e >> 6;                   // row in half, 0..127
  int b_in_row = (e << 1) & 127;     // dest byte in row (even)
  int kl = (b_in_row ^ ((lr & 7) << 4)) >> 1;
  int plane = lr >> 6;
  int f = fb * 128 + half * 64 + (lr & 63);
  int k = kkt * 64 + kl;
  float v = (f < F_BINS) ? (plane ? wcos[f * NFFT + k] : wsin[f * NFFT + k]) : 0.0f;
  *(uint16_t*)(wbt + (size_t)blob * 16384 + lr * 128 + b_in_row) = f2bf(v);
}

// ---- prep: gammatone bf16 [64][1152] ------------------------------------
__global__ __launch_bounds__(256) void build_gb(const float* __restrict__ g,
                                                uint16_t* __restrict__ gb) {
  int i = blockIdx.x * 256 + threadIdx.x;     // 64*1152
  int n = i / FPAD;
  int f = i - n * FPAD;
  gb[i] = f2bf(f < F_BINS ? g[n * F_BINS + f] : 0.0f);
}

// ---- main: 256x256 tile, BK=64, 8 waves (2Mx4N), 4-phase counted-vmcnt ---
#define AS_OFF(buf)   ((buf) * 65536)
#define BS_OFF(buf)   ((buf) * 65536 + 32768)

__global__ __launch_bounds__(512, 2) void gammatone_main(
    const char* __restrict__ xbp, const char* __restrict__ wbt,
    const char* __restrict__ gb, float* __restrict__ out) {
  __shared__ __align__(16) char smem[131072];

  const int tid = threadIdx.x;
  const int w = tid >> 6, l = tid & 63;
  const int lgrp = l >> 4, l15 = l & 15;
  const int wr = w >> 2, wc = w & 3;
  const int jb = blockIdx.x, fb = blockIdx.y;
  const int j0 = jb * 256;
  const int f0 = fb * 128;

  // B-staging per-thread source bases (pre-swizzled global address, m173):
  // dest byte t*16 -> row tid>>3, byte-in-row (tid&7)*16;
  // src k-byte = destbyte ^ ((row&7)<<4)
  const int xr = (((tid & 7) << 4)) ^ ((((tid >> 3) & 7)) << 4);
  size_t fbase[2][2];
#pragma unroll
  for (int h = 0; h < 2; ++h)
#pragma unroll
    for (int i = 0; i < 2; ++i) {
      int col = j0 + h * 128 + i * 64 + (tid >> 3);
      if (col > J_TOT - 1) col = J_TOT - 1;   // padded cols: garbage, never written
      int b = col / T_FR;
      int t = col - b * T_FR;
      fbase[h][i] = (size_t)b * ROWB + (size_t)t * 1024 + (size_t)xr;
    }

  const size_t wblob0 = (size_t)fb * 32 * 2 * 16384;

#define STAGE_A(kkt, buf) do {                                              \
    const char* g_ = wbt + wblob0 + (size_t)(kkt) * 32768;                  \
    char* d_ = smem + AS_OFF(buf);                                          \
    GLD16(g_ + w * 1024 + l * 16,         d_ + w * 1024 + l * 16);          \
    GLD16(g_ + 8192 + w * 1024 + l * 16,  d_ + 8192 + w * 1024 + l * 16);   \
    GLD16(g_ + 16384 + w * 1024 + l * 16, d_ + 16384 + w * 1024 + l * 16);  \
    GLD16(g_ + 24576 + w * 1024 + l * 16, d_ + 24576 + w * 1024 + l * 16);  \
  } while (0)

#define STAGE_B(kkt, buf, h) do {                                           \
    char* d_ = smem + BS_OFF(buf) + (h) * 16384;                            \
    GLD16(xbp + fbase[h][0] + (size_t)(kkt) * 128, d_ + w * 1024 + l * 16); \
    GLD16(xbp + fbase[h][1] + (size_t)(kkt) * 128, d_ + 8192 + w * 1024 + l * 16); \
  } while (0)

  // ---- prologue: K0 (A+B) -> buf0, K1.B -> buf1 (12 loads, oldest 8 = K0)
  STAGE_A(0, 0);
  STAGE_B(0, 0, 0); STAGE_B(0, 0, 1);
  STAGE_B(1, 1, 0); STAGE_B(1, 1, 1);
  asm volatile("s_waitcnt vmcnt(4)" ::: "memory");
  __builtin_amdgcn_s_barrier();

  f32x4 acc[8][4];
#pragma unroll
  for (int m = 0; m < 8; ++m)
#pragma unroll
    for (int n = 0; n < 4; ++n) acc[m][n] = (f32x4){0.f, 0.f, 0.f, 0.f};

  const int jrb = (wc & 1) * 64;   // B row base within its half

  for (int kk = 0; kk < 32; ++kk) {
    const int P = kk & 1, Q = P ^ 1;
    const char* Ab = smem + AS_OFF(P) + wr * 16384;
    const char* Bb = smem + BS_OFF(P) + (wc >> 1) * 16384;
    bf16x8 bv[4][2];

    // ---------- phase 0: all B frags + A m={0,1}; stage A(kk+1) ----------
    {
      bf16x8 av[2][2];
#pragma unroll
      for (int n = 0; n < 4; ++n)
#pragma unroll
        for (int s = 0; s < 2; ++s) {
          int row = jrb + n * 16 + l15;
          bv[n][s] = *(const bf16x8*)(Bb + row * 128 + ((s * 64 + lgrp * 16) ^ ((row & 7) << 4)));
        }
#pragma unroll
      for (int m = 0; m < 2; ++m)
#pragma unroll
        for (int s = 0; s < 2; ++s) {
          int row = m * 16 + l15;
          av[m][s] = *(const bf16x8*)(Ab + row * 128 + ((s * 64 + lgrp * 16) ^ ((row & 7) << 4)));
        }
      if (kk < 31) STAGE_A(kk + 1, Q);
      __builtin_amdgcn_s_barrier();
      asm volatile("s_waitcnt lgkmcnt(0)" ::: "memory");
      __builtin_amdgcn_s_setprio(1);
#pragma unroll
      for (int m = 0; m < 2; ++m)
#pragma unroll
        for (int n = 0; n < 4; ++n) {
          acc[m][n] = mfma16(av[m][0], bv[n][0], acc[m][n]);
          acc[m][n] = mfma16(av[m][1], bv[n][1], acc[m][n]);
        }
      __builtin_amdgcn_s_setprio(0);
      __builtin_amdgcn_s_barrier();
    }
    // ---------- phase 1: A m={2,3}; stage B(kk+2, half0) into buf P ------
    {
      bf16x8 av[2][2];
#pragma unroll
      for (int m = 0; m < 2; ++m)
#pragma unroll
        for (int s = 0; s < 2; ++s) {
          int row = (m + 2) * 16 + l15;
          av[m][s] = *(const bf16x8*)(Ab + row * 128 + ((s * 64 + lgrp * 16) ^ ((row & 7) << 4)));
        }
      if (kk < 30) STAGE_B(kk + 2, P, 0);
      __builtin_amdgcn_s_barrier();
      asm volatile("s_waitcnt lgkmcnt(0)" ::: "memory");
      __builtin_amdgcn_s_setprio(1);
#pragma unroll
      for (int m = 0; m < 2; ++m)
#pragma unroll
        for (int n = 0; n < 4; ++n) {
          acc[m + 2][n] = mfma16(av[m][0], bv[n][0], acc[m + 2][n]);
          acc[m + 2][n] = mfma16(av[m][1], bv[n][1], acc[m + 2][n]);
        }
      __builtin_amdgcn_s_setprio(0);
      __builtin_amdgcn_s_barrier();
    }
    // ---------- phase 2: A m={4,5}; stage B(kk+2, half1) -----------------
    {
      bf16x8 av[2][2];
#pragma unroll
      for (int m = 0; m < 2; ++m)
#pragma unroll
        for (int s = 0; s < 2; ++s) {
          int row = (m + 4) * 16 + l15;
          av[m][s] = *(const bf16x8*)(Ab + row * 128 + ((s * 64 + lgrp * 16) ^ ((row & 7) << 4)));
        }
      if (kk < 30) STAGE_B(kk + 2, P, 1);
      __builtin_amdgcn_s_barrier();
      asm volatile("s_waitcnt lgkmcnt(0)" ::: "memory");
      __builtin_amdgcn_s_setprio(1);
#pragma unroll
      for (int m = 0; m < 2; ++m)
#pragma unroll
        for (int n = 0; n < 4; ++n) {
          acc[m + 4][n] = mfma16(av[m][0], bv[n][0], acc[m + 4][n]);
          acc[m + 4][n] = mfma16(av[m][1], bv[n][1], acc[m + 4][n]);
        }
      __builtin_amdgcn_s_setprio(0);
      __builtin_amdgcn_s_barrier();
    }
    // ---------- phase 3: A m={6,7}; counted vmcnt for kk+1 readiness -----
    {
      bf16x8 av[2][2];
#pragma unroll
      for (int m = 0; m < 2; ++m)
#pragma unroll
        for (int s = 0; s < 2; ++s) {
          int row = (m + 6) * 16 + l15;
          av[m][s] = *(const bf16x8*)(Ab + row * 128 + ((s * 64 + lgrp * 16) ^ ((row & 7) << 4)));
        }
      // outstanding: B(kk+1) 4 + A(kk+1) 4 + B(kk+2) 4 -> oldest 8 = kk+1
      if (kk < 30)      asm volatile("s_waitcnt vmcnt(4)" ::: "memory");
      else if (kk == 30) asm volatile("s_waitcnt vmcnt(0)" ::: "memory");
      __builtin_amdgcn_s_barrier();
      asm volatile("s_waitcnt lgkmcnt(0)" ::: "memory");
      __builtin_amdgcn_s_setprio(1);
#pragma unroll
      for (int m = 0; m < 2; ++m)
#pragma unroll
        for (int n = 0; n < 4; ++n) {
          acc[m + 6][n] = mfma16(av[m][0], bv[n][0], acc[m + 6][n]);
          acc[m + 6][n] = mfma16(av[m][1], bv[n][1], acc[m + 6][n]);
        }
      __builtin_amdgcn_s_setprio(0);
      __builtin_amdgcn_s_barrier();
    }
  }

  __syncthreads();
  // spec = s^2 + c^2 -> LDS [j 256][f 128] bf16, swizzled byte = j*256 + ((fi*2) ^ ((j&7)<<4))
  // acc rows: m=0..3 sin, m+4 cos, fi = wr*64 + m*16 + lgrp*4 + r
#pragma unroll
  for (int m = 0; m < 4; ++m) {
    int fi = wr * 64 + m * 16 + lgrp * 4;
#pragma unroll
    for (int n = 0; n < 4; ++n) {
      int j = wc * 64 + n * 16 + l15;
      f32x4 s = acc[m][n], c = acc[m + 4][n];
      uint32_t lo = (uint32_t)f2bf(s.x * s.x + c.x * c.x) |
                    ((uint32_t)f2bf(s.y * s.y + c.y * c.y) << 16);
      uint32_t hi = (uint32_t)f2bf(s.z * s.z + c.z * c.z) |
                    ((uint32_t)f2bf(s.w * s.w + c.w * c.w) << 16);
      int off = j * 256 + ((fi * 2) ^ ((j & 7) << 4));
      *(u32x2*)(smem + off) = (u32x2){lo, hi};
    }
  }
  __syncthreads();

  // second GEMM: out_part[64][256j] = G[64][f0:+128] x spec[128][256]
  // wave w owns j range [w*32, +32)
  f32x4 acc2[4][2];
#pragma unroll
  for (int m = 0; m < 4; ++m) {
    acc2[m][0] = (f32x4){0.f, 0.f, 0.f, 0.f};
    acc2[m][1] = (f32x4){0.f, 0.f, 0.f, 0.f};
  }
  const int jq = w * 32;
#pragma unroll
  for (int ks = 0; ks < 4; ++ks) {
    bf16x8 gf[4], sf[2];
#pragma unroll
    for (int m2 = 0; m2 < 4; ++m2) {
      int grow = m2 * 16 + l15;
      gf[m2] = *(const bf16x8*)(gb + ((size_t)grow * FPAD + f0 + ks * 32 + lgrp * 8) * 2);
    }
#pragma unroll
    for (int nf = 0; nf < 2; ++nf) {
      int j = jq + nf * 16 + l15;
      sf[nf] = *(const bf16x8*)(smem + j * 256 + (((ks * 32 + lgrp * 8) * 2) ^ ((j & 7) << 4)));
    }
#pragma unroll
    for (int m2 = 0; m2 < 4; ++m2)
#pragma unroll
      for (int nf = 0; nf < 2; ++nf)
        acc2[m2][nf] = mfma16(gf[m2], sf[nf], acc2[m2][nf]);
  }

#pragma unroll
  for (int nf = 0; nf < 2; ++nf) {
    int jg = j0 + jq + nf * 16 + l15;
    if (jg < J_TOT) {
      int b = jg / T_FR;
      int t = jg - b * T_FR;
      float* ob = out + (size_t)(b * NB) * T_FR + t;
#pragma unroll
      for (int m2 = 0; m2 < 4; ++m2)
#pragma unroll
        for (int r = 0; r < 4; ++r) {
          int nout = m2 * 16 + lgrp * 4 + r;
          atomicAdd(ob + (size_t)nout * T_FR, acc2[m2][nf][r]);
        }
    }
  }
}

extern "C" void kernel_launch(void* const* d_in, const int* in_sizes, int n_in,
                              void* d_out, int out_size, void* d_ws, size_t ws_size,
                              hipStream_t stream) {
  (void)in_sizes; (void)n_in;
  const float* x    = (const float*)d_in[0];
  const float* wsin = (const float*)d_in[1];
  const float* wcos = (const float*)d_in[2];
  const float* g    = (const float*)d_in[3];
  if (ws_size < (size_t)WS_NEED) return;  // need ~38 MB scratch
  char* ws = (char*)d_ws;
  uint16_t* xbp = (uint16_t*)(ws + XBP_OFF);
  char*     wbt = ws + WBT_OFF;
  uint16_t* gbp = (uint16_t*)(ws + GB_OFF);

  hipMemsetAsync(d_out, 0, (size_t)out_size * sizeof(float), stream);
  build_xbp<<<(B_SZ * LP) / 256, 256, 0, stream>>>(x, xbp);
  build_wbt<<<(WBT_BYTES / 2) / 256, 256, 0, stream>>>(wsin, wcos, wbt);
  build_gb<<<(NB * FPAD) / 256, 256, 0, stream>>>(g, gbp);
  gammatone_main<<<dim3(NT_J, NT_F), 512, 0, stream>>>(
      (const char*)xbp, wbt, (const char*)gbp, (float*)d_out);
}

// Round 3
// 278.669 us; speedup vs baseline: 1.1830x; 1.1830x over previous
//
#include <hip/hip_runtime.h>
#include <stdint.h>

typedef __attribute__((ext_vector_type(4))) float f32x4;
typedef __attribute__((ext_vector_type(8))) short bf16x8;
typedef __attribute__((ext_vector_type(2))) unsigned int u32x2;

#define B_SZ   32
#define L_AUD  441000
#define PAD_A  1024
#define LP     443048          // L_AUD + 2*PAD_A
#define T_FR   862
#define J_TOT  27584           // B_SZ * T_FR
#define JPAD   27648           // 108 * 256
#define F_BINS 1025
#define NFFT   2048
#define NB     64
#define FPAD   1152            // 9 * 128
#define NT_J   108             // 27648 / 256
#define NT_F   9
#define NWG    (NT_J * NT_F)   // 972
#define ROWB   886096          // LP * 2 bytes per xbp row

#define XBP_OFF   0
#define XBP_BYTES (B_SZ * LP * 2)             // 28,355,072
#define WBT_OFF   XBP_BYTES
#define WBT_BYTES (NT_F * 32 * 2 * 16384)     // 9,437,184
#define GB_OFF    (WBT_OFF + WBT_BYTES)
#define GB_BYTES  (NB * FPAD * 2)             // 147,456
#define WS_NEED   (GB_OFF + GB_BYTES)         // 37,939,712
#define SLAB_OFF  WS_NEED
#define SLAB_BYTES ((size_t)NT_F * NB * JPAD * 4)   // 63,700,992
#define WS_BIG    (SLAB_OFF + SLAB_BYTES)     // 101,640,704

__device__ __forceinline__ uint16_t f2bf(float f) {
  union { float f; uint32_t u; } c; c.f = f;
  uint32_t r = c.u + 0x7FFFu + ((c.u >> 16) & 1u);
  return (uint16_t)(r >> 16);
}

__device__ __forceinline__ f32x4 mfma16(bf16x8 a, bf16x8 b, f32x4 c) {
  return __builtin_amdgcn_mfma_f32_16x16x32_bf16(a, b, c, 0, 0, 0);
}

#define GLD16(g, l) __builtin_amdgcn_global_load_lds( \
    (__attribute__((address_space(1))) void*)(g),     \
    (__attribute__((address_space(3))) void*)(l), 16, 0, 0)

// ---- prep: reflect-padded bf16 audio ------------------------------------
__global__ __launch_bounds__(256) void build_xbp(const float* __restrict__ x,
                                                 uint16_t* __restrict__ xbp) {
  int i = blockIdx.x * 256 + threadIdx.x;
  int b = i / LP;
  int p = i - b * LP;
  int s = p - PAD_A;
  s = s < 0 ? -s : s;
  s = s >= L_AUD ? (2 * L_AUD - 2 - s) : s;
  xbp[i] = f2bf(x[b * L_AUD + s]);
}

// ---- prep: W blobs (pre-swizzled linear staging order) -------------------
__global__ __launch_bounds__(256) void build_wbt(const float* __restrict__ wsin,
                                                 const float* __restrict__ wcos,
                                                 char* __restrict__ wbt) {
  int idx = blockIdx.x * 256 + threadIdx.x;
  int e = idx & 8191;
  int blob = idx >> 13;
  int half = blob & 1;
  int kkt = (blob >> 1) & 31;
  int fb = blob >> 6;
  int lr = e >> 6;
  int b_in_row = (e << 1) & 127;
  int kl = (b_in_row ^ ((lr & 7) << 4)) >> 1;
  int plane = lr >> 6;
  int f = fb * 128 + half * 64 + (lr & 63);
  int k = kkt * 64 + kl;
  float v = (f < F_BINS) ? (plane ? wcos[f * NFFT + k] : wsin[f * NFFT + k]) : 0.0f;
  *(uint16_t*)(wbt + (size_t)blob * 16384 + lr * 128 + b_in_row) = f2bf(v);
}

// ---- prep: gammatone bf16 [64][1152] ------------------------------------
__global__ __launch_bounds__(256) void build_gb(const float* __restrict__ g,
                                                uint16_t* __restrict__ gb) {
  int i = blockIdx.x * 256 + threadIdx.x;
  int n = i / FPAD;
  int f = i - n * FPAD;
  gb[i] = f2bf(f < F_BINS ? g[n * F_BINS + f] : 0.0f);
}

// ---- reduce: out[b][n][t] = sum_fb slab[fb][n][b*862+t] ------------------
__global__ __launch_bounds__(256) void reduce9(const float* __restrict__ slab,
                                               float* __restrict__ out) {
  int i = blockIdx.x * 256 + threadIdx.x;
  if (i >= J_TOT * NB) return;
  int b = i / (NB * T_FR);
  int rem = i - b * (NB * T_FR);
  int n = rem / T_FR;
  int t = rem - n * T_FR;
  int j = b * T_FR + t;
  float s = 0.f;
#pragma unroll
  for (int fb = 0; fb < NT_F; ++fb)
    s += slab[((size_t)fb * NB + n) * JPAD + j];
  out[i] = s;
}

// ---- main: 256x256 tile, BK=64, 8 waves, 4-phase counted-vmcnt -----------
#define AS_OFF(buf)   ((buf) * 65536)
#define BS_OFF(buf)   ((buf) * 65536 + 32768)

template <bool USE_SLAB>
__global__ __launch_bounds__(512, 2) void gammatone_main(
    const char* __restrict__ xbp, const char* __restrict__ wbt,
    const char* __restrict__ gb, float* __restrict__ dst) {
  __shared__ __align__(16) char smem[131072];

  const int tid = threadIdx.x;
  const int w = tid >> 6, l = tid & 63;
  const int lgrp = l >> 4, l15 = l & 15;
  const int wr = w >> 2, wc = w & 3;

  // bijective XCD swizzle (m204), fb-major work order: same-XCD blocks share
  // one wbt slice (L2-resident); B-frames stream from L3.
  const int orig = blockIdx.y * NT_J + blockIdx.x;
  const int xcd = orig & 7, slot = orig >> 3;
  const int q = NWG / 8, r = NWG & 7;            // 121, 4
  const int wkid = (xcd < r ? xcd * (q + 1) : r * (q + 1) + (xcd - r) * q) + slot;
  const int fb = wkid / NT_J;
  const int jb = wkid - fb * NT_J;
  const int j0 = jb * 256;
  const int f0 = fb * 128;

  const int xr = (((tid & 7) << 4)) ^ ((((tid >> 3) & 7)) << 4);
  size_t fbase[2][2];
#pragma unroll
  for (int h = 0; h < 2; ++h)
#pragma unroll
    for (int i = 0; i < 2; ++i) {
      int col = j0 + h * 128 + i * 64 + (tid >> 3);
      if (col > J_TOT - 1) col = J_TOT - 1;
      int b = col / T_FR;
      int t = col - b * T_FR;
      fbase[h][i] = (size_t)b * ROWB + (size_t)t * 1024 + (size_t)xr;
    }

  const size_t wblob0 = (size_t)fb * 32 * 2 * 16384;

#define STAGE_A(kkt, buf) do {                                              \
    const char* g_ = wbt + wblob0 + (size_t)(kkt) * 32768;                  \
    char* d_ = smem + AS_OFF(buf);                                          \
    GLD16(g_ + w * 1024 + l * 16,         d_ + w * 1024 + l * 16);          \
    GLD16(g_ + 8192 + w * 1024 + l * 16,  d_ + 8192 + w * 1024 + l * 16);   \
    GLD16(g_ + 16384 + w * 1024 + l * 16, d_ + 16384 + w * 1024 + l * 16);  \
    GLD16(g_ + 24576 + w * 1024 + l * 16, d_ + 24576 + w * 1024 + l * 16);  \
  } while (0)

#define STAGE_B(kkt, buf, h) do {                                           \
    char* d_ = smem + BS_OFF(buf) + (h) * 16384;                            \
    GLD16(xbp + fbase[h][0] + (size_t)(kkt) * 128, d_ + w * 1024 + l * 16); \
    GLD16(xbp + fbase[h][1] + (size_t)(kkt) * 128, d_ + 8192 + w * 1024 + l * 16); \
  } while (0)

  STAGE_A(0, 0);
  STAGE_B(0, 0, 0); STAGE_B(0, 0, 1);
  STAGE_B(1, 1, 0); STAGE_B(1, 1, 1);
  asm volatile("s_waitcnt vmcnt(4)" ::: "memory");
  __builtin_amdgcn_s_barrier();

  f32x4 acc[8][4];
#pragma unroll
  for (int m = 0; m < 8; ++m)
#pragma unroll
    for (int n = 0; n < 4; ++n) acc[m][n] = (f32x4){0.f, 0.f, 0.f, 0.f};

  const int jrb = (wc & 1) * 64;

  for (int kk = 0; kk < 32; ++kk) {
    const int P = kk & 1, Q = P ^ 1;
    const char* Ab = smem + AS_OFF(P) + wr * 16384;
    const char* Bb = smem + BS_OFF(P) + (wc >> 1) * 16384;
    bf16x8 bv[4][2];

    // phase 0: all B frags + A m={0,1}; stage A(kk+1)
    {
      bf16x8 av[2][2];
#pragma unroll
      for (int n = 0; n < 4; ++n)
#pragma unroll
        for (int s = 0; s < 2; ++s) {
          int row = jrb + n * 16 + l15;
          bv[n][s] = *(const bf16x8*)(Bb + row * 128 + ((s * 64 + lgrp * 16) ^ ((row & 7) << 4)));
        }
#pragma unroll
      for (int m = 0; m < 2; ++m)
#pragma unroll
        for (int s = 0; s < 2; ++s) {
          int row = m * 16 + l15;
          av[m][s] = *(const bf16x8*)(Ab + row * 128 + ((s * 64 + lgrp * 16) ^ ((row & 7) << 4)));
        }
      if (kk < 31) STAGE_A(kk + 1, Q);
      __builtin_amdgcn_s_barrier();
      asm volatile("s_waitcnt lgkmcnt(0)" ::: "memory");
      __builtin_amdgcn_s_setprio(1);
#pragma unroll
      for (int m = 0; m < 2; ++m)
#pragma unroll
        for (int n = 0; n < 4; ++n) {
          acc[m][n] = mfma16(av[m][0], bv[n][0], acc[m][n]);
          acc[m][n] = mfma16(av[m][1], bv[n][1], acc[m][n]);
        }
      __builtin_amdgcn_s_setprio(0);
      __builtin_amdgcn_s_barrier();
    }
    // phase 1: A m={2,3}; stage B(kk+2, half0)
    {
      bf16x8 av[2][2];
#pragma unroll
      for (int m = 0; m < 2; ++m)
#pragma unroll
        for (int s = 0; s < 2; ++s) {
          int row = (m + 2) * 16 + l15;
          av[m][s] = *(const bf16x8*)(Ab + row * 128 + ((s * 64 + lgrp * 16) ^ ((row & 7) << 4)));
        }
      if (kk < 30) STAGE_B(kk + 2, P, 0);
      __builtin_amdgcn_s_barrier();
      asm volatile("s_waitcnt lgkmcnt(0)" ::: "memory");
      __builtin_amdgcn_s_setprio(1);
#pragma unroll
      for (int m = 0; m < 2; ++m)
#pragma unroll
        for (int n = 0; n < 4; ++n) {
          acc[m + 2][n] = mfma16(av[m][0], bv[n][0], acc[m + 2][n]);
          acc[m + 2][n] = mfma16(av[m][1], bv[n][1], acc[m + 2][n]);
        }
      __builtin_amdgcn_s_setprio(0);
      __builtin_amdgcn_s_barrier();
    }
    // phase 2: A m={4,5}; stage B(kk+2, half1)
    {
      bf16x8 av[2][2];
#pragma unroll
      for (int m = 0; m < 2; ++m)
#pragma unroll
        for (int s = 0; s < 2; ++s) {
          int row = (m + 4) * 16 + l15;
          av[m][s] = *(const bf16x8*)(Ab + row * 128 + ((s * 64 + lgrp * 16) ^ ((row & 7) << 4)));
        }
      if (kk < 30) STAGE_B(kk + 2, P, 1);
      __builtin_amdgcn_s_barrier();
      asm volatile("s_waitcnt lgkmcnt(0)" ::: "memory");
      __builtin_amdgcn_s_setprio(1);
#pragma unroll
      for (int m = 0; m < 2; ++m)
#pragma unroll
        for (int n = 0; n < 4; ++n) {
          acc[m + 4][n] = mfma16(av[m][0], bv[n][0], acc[m + 4][n]);
          acc[m + 4][n] = mfma16(av[m][1], bv[n][1], acc[m + 4][n]);
        }
      __builtin_amdgcn_s_setprio(0);
      __builtin_amdgcn_s_barrier();
    }
    // phase 3: A m={6,7}; counted vmcnt for kk+1 readiness
    {
      bf16x8 av[2][2];
#pragma unroll
      for (int m = 0; m < 2; ++m)
#pragma unroll
        for (int s = 0; s < 2; ++s) {
          int row = (m + 6) * 16 + l15;
          av[m][s] = *(const bf16x8*)(Ab + row * 128 + ((s * 64 + lgrp * 16) ^ ((row & 7) << 4)));
        }
      if (kk < 30)       asm volatile("s_waitcnt vmcnt(4)" ::: "memory");
      else if (kk == 30) asm volatile("s_waitcnt vmcnt(0)" ::: "memory");
      __builtin_amdgcn_s_barrier();
      asm volatile("s_waitcnt lgkmcnt(0)" ::: "memory");
      __builtin_amdgcn_s_setprio(1);
#pragma unroll
      for (int m = 0; m < 2; ++m)
#pragma unroll
        for (int n = 0; n < 4; ++n) {
          acc[m + 6][n] = mfma16(av[m][0], bv[n][0], acc[m + 6][n]);
          acc[m + 6][n] = mfma16(av[m][1], bv[n][1], acc[m + 6][n]);
        }
      __builtin_amdgcn_s_setprio(0);
      __builtin_amdgcn_s_barrier();
    }
  }

  __syncthreads();
  // spec = s^2 + c^2 -> LDS [j 256][f 128] bf16 swizzled
#pragma unroll
  for (int m = 0; m < 4; ++m) {
    int fi = wr * 64 + m * 16 + lgrp * 4;
#pragma unroll
    for (int n = 0; n < 4; ++n) {
      int j = wc * 64 + n * 16 + l15;
      f32x4 s = acc[m][n], c = acc[m + 4][n];
      uint32_t lo = (uint32_t)f2bf(s.x * s.x + c.x * c.x) |
                    ((uint32_t)f2bf(s.y * s.y + c.y * c.y) << 16);
      uint32_t hi = (uint32_t)f2bf(s.z * s.z + c.z * c.z) |
                    ((uint32_t)f2bf(s.w * s.w + c.w * c.w) << 16);
      int off = j * 256 + ((fi * 2) ^ ((j & 7) << 4));
      *(u32x2*)(smem + off) = (u32x2){lo, hi};
    }
  }
  __syncthreads();

  // second GEMM: out_part[64][256j] = G[64][f0:+128] x spec[128][256]
  f32x4 acc2[4][2];
#pragma unroll
  for (int m = 0; m < 4; ++m) {
    acc2[m][0] = (f32x4){0.f, 0.f, 0.f, 0.f};
    acc2[m][1] = (f32x4){0.f, 0.f, 0.f, 0.f};
  }
  const int jq = w * 32;
#pragma unroll
  for (int ks = 0; ks < 4; ++ks) {
    bf16x8 gf[4], sf[2];
#pragma unroll
    for (int m2 = 0; m2 < 4; ++m2) {
      int grow = m2 * 16 + l15;
      gf[m2] = *(const bf16x8*)(gb + ((size_t)grow * FPAD + f0 + ks * 32 + lgrp * 8) * 2);
    }
#pragma unroll
    for (int nf = 0; nf < 2; ++nf) {
      int j = jq + nf * 16 + l15;
      sf[nf] = *(const bf16x8*)(smem + j * 256 + (((ks * 32 + lgrp * 8) * 2) ^ ((j & 7) << 4)));
    }
#pragma unroll
    for (int m2 = 0; m2 < 4; ++m2)
#pragma unroll
      for (int nf = 0; nf < 2; ++nf)
        acc2[m2][nf] = mfma16(gf[m2], sf[nf], acc2[m2][nf]);
  }

#pragma unroll
  for (int nf = 0; nf < 2; ++nf) {
    int jg = j0 + jq + nf * 16 + l15;
    if (USE_SLAB) {
      // plain stores into per-fb slab [fb][64 n][27648 j]
      float* sl = dst + ((size_t)fb * NB) * JPAD + jg;
#pragma unroll
      for (int m2 = 0; m2 < 4; ++m2)
#pragma unroll
        for (int r2 = 0; r2 < 4; ++r2) {
          int nout = m2 * 16 + lgrp * 4 + r2;
          sl[(size_t)nout * JPAD] = acc2[m2][nf][r2];
        }
    } else if (jg < J_TOT) {
      int b = jg / T_FR;
      int t = jg - b * T_FR;
      float* ob = dst + (size_t)(b * NB) * T_FR + t;
#pragma unroll
      for (int m2 = 0; m2 < 4; ++m2)
#pragma unroll
        for (int r2 = 0; r2 < 4; ++r2) {
          int nout = m2 * 16 + lgrp * 4 + r2;
          atomicAdd(ob + (size_t)nout * T_FR, acc2[m2][nf][r2]);
        }
    }
  }
}

extern "C" void kernel_launch(void* const* d_in, const int* in_sizes, int n_in,
                              void* d_out, int out_size, void* d_ws, size_t ws_size,
                              hipStream_t stream) {
  (void)in_sizes; (void)n_in;
  const float* x    = (const float*)d_in[0];
  const float* wsin = (const float*)d_in[1];
  const float* wcos = (const float*)d_in[2];
  const float* g    = (const float*)d_in[3];
  if (ws_size < (size_t)WS_NEED) return;
  char* ws = (char*)d_ws;
  uint16_t* xbp = (uint16_t*)(ws + XBP_OFF);
  char*     wbt = ws + WBT_OFF;
  uint16_t* gbp = (uint16_t*)(ws + GB_OFF);

  build_xbp<<<(B_SZ * LP) / 256, 256, 0, stream>>>(x, xbp);
  build_wbt<<<(WBT_BYTES / 2) / 256, 256, 0, stream>>>(wsin, wcos, wbt);
  build_gb<<<(NB * FPAD) / 256, 256, 0, stream>>>(g, gbp);

  if (ws_size >= (size_t)WS_BIG) {
    float* slab = (float*)(ws + SLAB_OFF);
    gammatone_main<true><<<dim3(NT_J, NT_F), 512, 0, stream>>>(
        (const char*)xbp, wbt, (const char*)gbp, slab);
    reduce9<<<(J_TOT * NB + 255) / 256, 256, 0, stream>>>(slab, (float*)d_out);
  } else {
    hipMemsetAsync(d_out, 0, (size_t)out_size * sizeof(float), stream);
    gammatone_main<false><<<dim3(NT_J, NT_F), 512, 0, stream>>>(
        (const char*)xbp, wbt, (const char*)gbp, (float*)d_out);
  }
}